// Round 5
// baseline (628.651 us; speedup 1.0000x reference)
//
#include <hip/hip_runtime.h>

// Problem is fixed-shape: B=8192, N=4096, M=4096, G=512, CB=256.
#define B_DIM 8192
#define N_DIM 4096
#define M_DIM 4096
#define G_DIM 512

typedef short bf16x8 __attribute__((ext_vector_type(8)));
typedef float f32x4 __attribute__((ext_vector_type(4)));

typedef __attribute__((address_space(1))) const void gvoid_t;
typedef __attribute__((address_space(3))) void lvoid_t;

__device__ __forceinline__ void load_lds16(const void* g, void* l) {
    __builtin_amdgcn_global_load_lds((gvoid_t*)g, (lvoid_t*)l, 16, 0, 0);
}

__device__ __forceinline__ unsigned short f2bf(float f) {
    union { float f; unsigned int u; } v; v.f = f;
    unsigned int u = v.u;
    unsigned int r = (u + 0x7fffu + ((u >> 16) & 1u)) >> 16;
    return (unsigned short)r;
}
__device__ __forceinline__ float bf2f(unsigned short s) {
    union { unsigned int u; float f; } v; v.u = ((unsigned int)s) << 16;
    return v.f;
}

// In-register H16 (unnormalized Hadamard over 16 values).
__device__ __forceinline__ void h16(float* v) {
#pragma unroll
    for (int h = 1; h < 16; h <<= 1) {
#pragma unroll
        for (int i = 0; i < 16; i++) {
            if (!(i & h)) {
                float a = v[i], b = v[i | h];
                v[i] = a + b;
                v[i | h] = a - b;
            }
        }
    }
}

// In-register H64 (unnormalized Hadamard over 64 values).
__device__ __forceinline__ void h64(float* v) {
#pragma unroll
    for (int h = 1; h < 64; h <<= 1) {
#pragma unroll
        for (int i = 0; i < 64; i++) {
            if (!(i & h)) {
                float a = v[i], b = v[i | h];
                v[i] = a + b;
                v[i | h] = a - b;
            }
        }
    }
}

// ---------------------------------------------------------------------------
// Kernel 1: W[m][g*8+j] = (cb1[q1[m][g]][j] + cb2[q2[m][g]][j]*irs) * Wscale
// ---------------------------------------------------------------------------
__global__ __launch_bounds__(256) void k_build_w(
    const int* __restrict__ q1, const int* __restrict__ q2,
    const float* __restrict__ cb1, const float* __restrict__ cb2,
    const float* __restrict__ wsp, const float* __restrict__ irsp,
    unsigned short* __restrict__ W) {
    __shared__ float c1[256 * 9];
    __shared__ float c2[256 * 9];
    int t = threadIdx.x;
#pragma unroll
    for (int j = 0; j < 8; j++) {
        c1[t * 9 + j] = cb1[t * 8 + j];
        c2[t * 9 + j] = cb2[t * 8 + j];
    }
    __syncthreads();
    float ws = wsp[0];
    float irs = irsp[0] * ws;
    int gid = blockIdx.x * 256 + t;  // exact multiple, no guard needed
    int i1 = q1[gid] * 9;
    int i2 = q2[gid] * 9;
    union { unsigned short s[8]; int4 v; } o;
#pragma unroll
    for (int j = 0; j < 8; j++) {
        o.s[j] = f2bf(c1[i1 + j] * ws + c2[i2 + j] * irs);
    }
    *(int4*)(W + (size_t)gid * 8) = o.v;
}

// ---------------------------------------------------------------------------
// Kernel 1b: column-direction Hadamard on W (in place, bf16). Two passes.
//   pass1: base_mul=1,  step=64, scale=1        (transform over hi)
//   pass2: base_mul=64, step=1,  scale=1/64     (transform over lo)
// ---------------------------------------------------------------------------
__global__ __launch_bounds__(256) void k_hadw(
    unsigned short* __restrict__ W, int base_mul, int step, float scale) {
    int c = blockIdx.x * 256 + threadIdx.x;
    int base = blockIdx.y * base_mul;
    float v[64];
#pragma unroll
    for (int j = 0; j < 64; j++)
        v[j] = bf2f(W[(size_t)(base + j * step) * N_DIM + c]);
    h64(v);
#pragma unroll
    for (int j = 0; j < 64; j++)
        W[(size_t)(base + j * step) * N_DIM + c] = f2bf(v[j] * scale);
}

// ---------------------------------------------------------------------------
// Kernel 2 (v2): x_rht = fht(x * SV) -> bf16. One WAVE (64 threads) per row.
// ---------------------------------------------------------------------------
__global__ __launch_bounds__(64) void k_rht_in(
    const float* __restrict__ x, const float* __restrict__ SV,
    unsigned short* __restrict__ out) {
    __shared__ float lds[4352];  // f(n) max 4350
    int u = threadIdx.x;  // 0..63
    int row = blockIdx.x;
    const float* xr = x + (size_t)row * N_DIM;
    float v[4][16];
    // phase A: transform over n2 (=r) at fixed class c = n&255 = 4u+i
#pragma unroll
    for (int r = 0; r < 16; r++) {
        int n = 4 * u + (r << 8);
        float4 a = *(const float4*)(xr + n);
        float4 s = *(const float4*)(SV + n);
        v[0][r] = a.x * s.x * 0.015625f;
        v[1][r] = a.y * s.y * 0.015625f;
        v[2][r] = a.z * s.z * 0.015625f;
        v[3][r] = a.w * s.w * 0.015625f;
    }
#pragma unroll
    for (int i = 0; i < 4; i++) h16(v[i]);
#pragma unroll
    for (int r = 0; r < 16; r++) {
#pragma unroll
        for (int i = 0; i < 4; i++) {
            int n = (r << 8) + 4 * u + i;
            lds[n + (n >> 4)] = v[i][r];
        }
    }
    __syncthreads();
    // phase B: transform over n0 at fixed g = n>>4; lane u: g = u + 64j.
#pragma unroll
    for (int j = 0; j < 4; j++) {
        int base = 17 * (u + (j << 6));
        float w[16];
#pragma unroll
        for (int n0 = 0; n0 < 16; n0++) w[n0] = lds[base + n0];
        h16(w);
#pragma unroll
        for (int n0 = 0; n0 < 16; n0++) lds[base + n0] = w[n0];
    }
    __syncthreads();
    // phase C: transform over n1 (=r) at fixed (n2, n0).
#pragma unroll
    for (int j = 0; j < 4; j++) {
        int base = 272 * ((u >> 4) + (j << 2)) + (u & 15);
        float w[16];
#pragma unroll
        for (int r = 0; r < 16; r++) w[r] = lds[base + 17 * r];
        h16(w);
#pragma unroll
        for (int r = 0; r < 16; r++) lds[base + 17 * r] = w[r];
    }
    __syncthreads();
    // store: lane u writes 8 contiguous bf16 at n = 8u + 512s (short8).
    unsigned short* orow = out + (size_t)row * N_DIM;
#pragma unroll
    for (int s = 0; s < 8; s++) {
        int n = 8 * u + (s << 9);
        union { unsigned short h[8]; int4 q; } o;
#pragma unroll
        for (int jj = 0; jj < 8; jj++) {
            int nn = n + jj;
            o.h[jj] = f2bf(lds[nn + (nn >> 4)]);
        }
        *(int4*)(orow + n) = o.q;
    }
}

// ---------------------------------------------------------------------------
// Kernel 3 (v5): y[b,m] = SU[m] * dot(x_rht[b,:], W''[m,:])   (NT GEMM)
//
// 256x256x(BK=32) tile, 8 waves (2Mx4N), per-wave 128x64, acc[8][4].
//
// KEY CHANGE vs r1-r4 (which all measured T_iter ~ DS + MFMA, serialized):
// break the intra-interval read->MFMA dependency so DS and MFMA overlap:
//   - B fragments: loaded DIRECTLY from global (L2-hot; 4MB B-panel per XCD
//     with the pairing map) into registers, DOUBLE-BUFFERED one K-tile ahead
//     (+16 VGPR). MFMAs of tile k use B regs loaded during iter k-1 -> no
//     same-interval dependency on B.
//   - A fragments: just-in-time from the swizzled LDS ring (8 ds_read_b128;
//     A-drain 64 reads/CU ~770cy < MFMA 1240cy, eligibility ramps at i/8).
//   - DS traffic -33% (B reads+stores gone); LDS ring now A-only:
//     4 x 16KB = 64KB.
// vmcnt discipline (single counted wait per iter, never 0): issue order per
// iter = [A-stage(k+3): 2][B(k+1): 4]. vmcnt(6) leaves exactly those 6 ->
// forces B(k) + A(k+1) landed. Prologue: [B(0):4][A(0..2):6], vmcnt(4)
// leaves A(1),A(2) -> B(0)+A(0) landed.
// Race: A-stage(k+3) overwrites buf[(k-1)&3]; its reads drained (consumed
// by MFMAs + lgkm(0)) before iter k-1's end barrier. Reads of buf[k&3]
// can't hoist above the end-of-iter barrier (memory-clobber fences).
// A-swizzle (rule 21) unchanged: 0 bank conflicts measured.
// XCD map v2 (A-pairing): bn = xcd*2 + (idx&1), bm = idx>>1 -> the 2
// concurrent blocks per (XCD, bm) share one A panel in L2.
// ---------------------------------------------------------------------------
__global__ __launch_bounds__(512, 2) void k_gemm(
    const unsigned short* __restrict__ A,   // (B_DIM, N_DIM) bf16
    const unsigned short* __restrict__ Bw,  // (M_DIM, N_DIM) bf16  (= W'')
    const float* __restrict__ SU,
    float* __restrict__ C) {                // (B_DIM, M_DIM) f32
    __shared__ __align__(16) unsigned short lds[4 * 8192];  // 64 KiB (A ring)

    int t = threadIdx.x;
    int w = t >> 6;   // wave 0..7
    int l = t & 63;

    // XCD-aware tile mapping, A-panel pairing (bijective, 512 % 8 == 0).
    int lin = blockIdx.x;
    int xcd = lin & 7;
    int idx = lin >> 3;             // 0..63
    int bn = xcd * 2 + (idx & 1);   // 0..15  (M tiles)
    int bm = idx >> 1;              // 0..31  (B tiles)

    // A staging: lane l writes LDS slot (row w*16 + l>>2, chunk l&3) of a
    // 128-row half; inverse-swizzled global source uses lx = l ^ (l>>3).
    int lx = l ^ (l >> 3);
    const unsigned short* aS0 =
        A + (size_t)(bm * 256 + w * 16 + (lx >> 2)) * N_DIM + (lx & 3) * 8;
    const unsigned short* aS1 = aS0 + (size_t)128 * N_DIM;

    // fragment geometry
    int wm = w >> 2;   // 0..1  (M half)
    int wn = w & 3;    // 0..3  (N quarter)
    int quad = l >> 4;
    int ln = l & 15;
    // A fragment LDS offset (elements, swizzled; 16B-aligned)
    unsigned aOff =
        (unsigned)((((wm * 128 + ln) << 6) | (quad << 4)) ^ ((ln >> 1) << 4)) >> 1;
    // B fragment global pointers: row (bn*256 + wn*64 + j*16 + ln), k-chunk
    // quad*8. Lanes {ln, quad0..3} cover 64B contiguous per row.
    const unsigned short* bp[4];
#pragma unroll
    for (int j = 0; j < 4; j++)
        bp[j] = Bw + (size_t)(bn * 256 + wn * 64 + j * 16 + ln) * N_DIM + quad * 8;

    f32x4 acc[8][4];
#pragma unroll
    for (int i = 0; i < 8; i++)
#pragma unroll
        for (int j = 0; j < 4; j++) {
            f32x4 z = {0.f, 0.f, 0.f, 0.f};
            acc[i][j] = z;
        }

#define STAGE_A(KT) do {                                            \
        int kt_ = (KT);                                             \
        int ks_ = kt_ < 127 ? kt_ : 127;                            \
        unsigned short* d_ = lds + ((unsigned)kt_ & 3u) * 8192 + w * 512; \
        load_lds16(aS0 + ks_ * 32, d_);                             \
        load_lds16(aS1 + ks_ * 32, d_ + 4096);                      \
    } while (0)

#define LOADB(DST, KT) do {                                         \
        int kb_ = (KT) < 127 ? (KT) : 127;                          \
        _Pragma("unroll")                                           \
        for (int j = 0; j < 4; j++)                                 \
            DST[j] = *(const bf16x8*)(bp[j] + kb_ * 32);            \
    } while (0)

    bf16x8 bA[4], bB[4];
    // prologue: B(0) first, then A(0..2); vmcnt(4) leaves A(1),A(2) in
    // flight -> B(0) and A(0) landed.
    LOADB(bA, 0);
    STAGE_A(0);
    STAGE_A(1);
    STAGE_A(2);
    asm volatile("s_waitcnt vmcnt(4)");
    __builtin_amdgcn_s_barrier();
    asm volatile("" ::: "memory");

#define BODY(K, BCUR, BNXT) do {                                    \
        STAGE_A((K) + 3);                                           \
        LOADB(BNXT, (K) + 1);                                       \
        const unsigned short* aP =                                  \
            lds + ((unsigned)(K) & 3u) * 8192u + aOff;              \
        bf16x8 af[8];                                               \
        _Pragma("unroll")                                           \
        for (int i = 0; i < 8; i++) af[i] = *(const bf16x8*)(aP + i * 512); \
        _Pragma("unroll")                                           \
        for (int i = 0; i < 8; i++)                                 \
            _Pragma("unroll")                                       \
            for (int j = 0; j < 4; j++)                             \
                acc[i][j] = __builtin_amdgcn_mfma_f32_16x16x32_bf16( \
                    af[i], BCUR[j], acc[i][j], 0, 0, 0);            \
        asm volatile("s_waitcnt lgkmcnt(0)");                       \
        asm volatile("s_waitcnt vmcnt(6)");                         \
        asm volatile("" ::: "memory");                              \
        __builtin_amdgcn_s_barrier();                               \
        asm volatile("" ::: "memory");                              \
    } while (0)

    for (int k = 0; k < N_DIM / 32; k += 2) {
        BODY(k, bA, bB);
        BODY(k + 1, bB, bA);
    }
    asm volatile("s_waitcnt vmcnt(0)");  // drain tail dummy stages/loads

    // epilogue: C/D layout col=lane&15, row=quad*4+reg (m89/m91-verified)
#pragma unroll
    for (int j = 0; j < 4; j++) {
        int col = bn * 256 + wn * 64 + j * 16 + ln;
        float su = SU[col];
#pragma unroll
        for (int i = 0; i < 8; i++) {
#pragma unroll
            for (int r = 0; r < 4; r++) {
                int rowg = bm * 256 + wm * 128 + i * 16 + quad * 4 + r;
                C[(size_t)rowg * M_DIM + col] = acc[i][j][r] * su;
            }
        }
    }
#undef STAGE_A
#undef LOADB
#undef BODY
}

extern "C" void kernel_launch(void* const* d_in, const int* in_sizes, int n_in,
                              void* d_out, int out_size, void* d_ws, size_t ws_size,
                              hipStream_t stream) {
    const float* x    = (const float*)d_in[0];
    const int*   q1   = (const int*)d_in[1];
    const int*   q2   = (const int*)d_in[2];
    const float* SU   = (const float*)d_in[3];
    const float* SV   = (const float*)d_in[4];
    const float* cb1  = (const float*)d_in[5];
    const float* cb2  = (const float*)d_in[6];
    const float* wsp  = (const float*)d_in[7];
    const float* irsp = (const float*)d_in[8];
    float* out = (float*)d_out;  // reference output dtype: float32

    // workspace: x_rht bf16 (64MiB) | W bf16 (32MiB)  => 96MiB total
    unsigned short* xrht = (unsigned short*)d_ws;
    unsigned short* Wb   = xrht + (size_t)B_DIM * N_DIM;

    k_build_w<<<dim3((M_DIM * G_DIM) / 256), dim3(256), 0, stream>>>(
        q1, q2, cb1, cb2, wsp, irsp, Wb);
    // W'' = (1/64) H_4096 W  (column-direction Hadamard, two H64 passes)
    k_hadw<<<dim3(N_DIM / 256, 64), dim3(256), 0, stream>>>(Wb, 1, 64, 1.0f);
    k_hadw<<<dim3(N_DIM / 256, 64), dim3(256), 0, stream>>>(Wb, 64, 1, 0.015625f);
    k_rht_in<<<dim3(B_DIM), dim3(64), 0, stream>>>(x, SV, xrht);
    k_gemm<<<dim3(512), dim3(512), 0, stream>>>(xrht, Wb, SU, out);
}

// Round 7
// 520.979 us; speedup vs baseline: 1.2067x; 1.2067x over previous
//
#include <hip/hip_runtime.h>

// Problem is fixed-shape: B=8192, N=4096, M=4096, G=512, CB=256.
#define B_DIM 8192
#define N_DIM 4096
#define M_DIM 4096
#define G_DIM 512

typedef short bf16x8 __attribute__((ext_vector_type(8)));
typedef float f32x4 __attribute__((ext_vector_type(4)));

typedef __attribute__((address_space(1))) const void gvoid_t;
typedef __attribute__((address_space(3))) void lvoid_t;

__device__ __forceinline__ void load_lds16(const void* g, void* l) {
    __builtin_amdgcn_global_load_lds((gvoid_t*)g, (lvoid_t*)l, 16, 0, 0);
}

// Generic->LDS addrspace cast; as3 pointers are 32-bit LDS byte offsets.
__device__ __forceinline__ unsigned lds_u32(const void* p) {
    return (unsigned)(unsigned long long)(lvoid_t*)p;
}

__device__ __forceinline__ unsigned short f2bf(float f) {
    union { float f; unsigned int u; } v; v.f = f;
    unsigned int u = v.u;
    unsigned int r = (u + 0x7fffu + ((u >> 16) & 1u)) >> 16;
    return (unsigned short)r;
}
__device__ __forceinline__ float bf2f(unsigned short s) {
    union { unsigned int u; float f; } v; v.u = ((unsigned int)s) << 16;
    return v.f;
}

// In-register H16 (unnormalized Hadamard over 16 values).
__device__ __forceinline__ void h16(float* v) {
#pragma unroll
    for (int h = 1; h < 16; h <<= 1) {
#pragma unroll
        for (int i = 0; i < 16; i++) {
            if (!(i & h)) {
                float a = v[i], b = v[i | h];
                v[i] = a + b;
                v[i | h] = a - b;
            }
        }
    }
}

// In-register H64 (unnormalized Hadamard over 64 values).
__device__ __forceinline__ void h64(float* v) {
#pragma unroll
    for (int h = 1; h < 64; h <<= 1) {
#pragma unroll
        for (int i = 0; i < 64; i++) {
            if (!(i & h)) {
                float a = v[i], b = v[i | h];
                v[i] = a + b;
                v[i | h] = a - b;
            }
        }
    }
}

// ---------------------------------------------------------------------------
// Kernel 1: W[m][g*8+j] = (cb1[q1[m][g]][j] + cb2[q2[m][g]][j]*irs) * Wscale
// ---------------------------------------------------------------------------
__global__ __launch_bounds__(256) void k_build_w(
    const int* __restrict__ q1, const int* __restrict__ q2,
    const float* __restrict__ cb1, const float* __restrict__ cb2,
    const float* __restrict__ wsp, const float* __restrict__ irsp,
    unsigned short* __restrict__ W) {
    __shared__ float c1[256 * 9];
    __shared__ float c2[256 * 9];
    int t = threadIdx.x;
#pragma unroll
    for (int j = 0; j < 8; j++) {
        c1[t * 9 + j] = cb1[t * 8 + j];
        c2[t * 9 + j] = cb2[t * 8 + j];
    }
    __syncthreads();
    float ws = wsp[0];
    float irs = irsp[0] * ws;
    int gid = blockIdx.x * 256 + t;  // exact multiple, no guard needed
    int i1 = q1[gid] * 9;
    int i2 = q2[gid] * 9;
    union { unsigned short s[8]; int4 v; } o;
#pragma unroll
    for (int j = 0; j < 8; j++) {
        o.s[j] = f2bf(c1[i1 + j] * ws + c2[i2 + j] * irs);
    }
    *(int4*)(W + (size_t)gid * 8) = o.v;
}

// ---------------------------------------------------------------------------
// Kernel 1b: column-direction Hadamard on W (in place, bf16). Two passes.
//   pass1: base_mul=1,  step=64, scale=1        (transform over hi)
//   pass2: base_mul=64, step=1,  scale=1/64     (transform over lo)
// ---------------------------------------------------------------------------
__global__ __launch_bounds__(256) void k_hadw(
    unsigned short* __restrict__ W, int base_mul, int step, float scale) {
    int c = blockIdx.x * 256 + threadIdx.x;
    int base = blockIdx.y * base_mul;
    float v[64];
#pragma unroll
    for (int j = 0; j < 64; j++)
        v[j] = bf2f(W[(size_t)(base + j * step) * N_DIM + c]);
    h64(v);
#pragma unroll
    for (int j = 0; j < 64; j++)
        W[(size_t)(base + j * step) * N_DIM + c] = f2bf(v[j] * scale);
}

// ---------------------------------------------------------------------------
// Kernel 2: x_rht = fht(x * SV) -> bf16 (R1 256-thread version, known-best).
// ---------------------------------------------------------------------------
__global__ __launch_bounds__(256) void k_rht_in(
    const float* __restrict__ x, const float* __restrict__ SV,
    unsigned short* __restrict__ out) {
    __shared__ float lds[4352];  // f(n) = n + (n>>4), max 4350
    int row = blockIdx.x;
    int t = threadIdx.x;
    const float* xr = x + (size_t)row * N_DIM;
    float v[16];
    // phase A: n = t + 256r
#pragma unroll
    for (int r = 0; r < 16; r++) {
        int n = t + (r << 8);
        v[r] = xr[n] * SV[n] * 0.015625f;
    }
    h16(v);
#pragma unroll
    for (int r = 0; r < 16; r++) { int n = t + (r << 8); lds[n + (n >> 4)] = v[r]; }
    __syncthreads();
    // phase B: n = 16t + r
#pragma unroll
    for (int r = 0; r < 16; r++) { int n = (t << 4) + r; v[r] = lds[n + (n >> 4)]; }
    h16(v);
#pragma unroll
    for (int r = 0; r < 16; r++) { int n = (t << 4) + r; lds[n + (n >> 4)] = v[r]; }
    __syncthreads();
    // phase C: n = (t&15) | (r<<4) | ((t>>4)<<8)
#pragma unroll
    for (int r = 0; r < 16; r++) {
        int n = (t & 15) | (r << 4) | ((t >> 4) << 8);
        v[r] = lds[n + (n >> 4)];
    }
    h16(v);
#pragma unroll
    for (int r = 0; r < 16; r++) {
        int n = (t & 15) | (r << 4) | ((t >> 4) << 8);
        lds[n + (n >> 4)] = v[r];
    }
    __syncthreads();
    unsigned short* orow = out + (size_t)row * N_DIM;
#pragma unroll
    for (int r = 0; r < 16; r++) {
        int n = t + (r << 8);
        orow[n] = f2bf(lds[n + (n >> 4)]);
    }
}

// ---------------------------------------------------------------------------
// Kernel 3 (v6b): y[b,m] = SU[m] * dot(x_rht[b,:], W''[m,:])   (NT GEMM)
//
// Identical to v6 (R6) except the PROLOGUE RACE FIX: prologue waits
// vmcnt(4), not vmcnt(8). R6's vmcnt(8) only guaranteed tile 0 resident,
// but BODY(0) issues ds_reads of tile 1 mid-body -> read-before-write race
// (absmax 32.5 failure). vmcnt(4) with 12 staging loads issued leaves only
// STAGE(2) in flight => tiles 0 AND 1 landed, matching the steady-state
// invariant "end-of-iter-(k-1) vmcnt(4) => tile k+1 resident".
//
// v6 mechanism (from R1-R5 invariant T_iter ~ DS + MFMA serialized):
// per-wave IN-ORDER issue + same-interval RAW was the serializer. Fix:
//   - reads issued in iter k target tile k+1 (NO RAW with iter-k MFMAs);
//   - 1:1 interleave of MFMA groups and next-tile ds_reads, pinned with
//     sched_group_barrier (T19): [VMEM stage x4][{MFMA x4, DS x1-2} x8];
//   - bfr double-buffered (bfrA/bfrB, +16 VGPR); af[i] re-read placed
//     right after GROUP(i) (SSA: old/new af are separate vregs, liveness
//     disjoint);
//   - lgkmcnt(0)+sched_barrier(0) at TOP of body (rule 18): waits reads
//     issued a full iteration ago (~free), keeps MFMAs below it;
//   - counted vmcnt(4) per iter, never 0.
// Race audit (all waves):
//   - reads of tile k+1 in iter k: STAGE(k+1) landed by end-of-iter-(k-1)
//     vmcnt(4) [prologue now conforms] + barrier.
//   - STAGE(k+3) overwrites buf[(k-1)&3]: tile-(k-1) reads issued iter k-2,
//     drained at top-of-iter-(k-1) lgkmcnt(0), ordered by its end barrier.
//   - k=127 reads "tile 128" (stale buf 0 data, resident, never consumed).
// LDS swizzle (rule 21) unchanged from R1: 0 bank conflicts measured.
// XCD swizzle: R1 map (each XCD: 2 bn-columns x 32 bm).
// ---------------------------------------------------------------------------
#define DSR(D, A, OFF) \
    asm volatile("ds_read_b128 %0, %1 offset:" #OFF : "=v"(D) : "v"(A))
#define SB0() __builtin_amdgcn_sched_barrier(0)
#define SGB(M, N) __builtin_amdgcn_sched_group_barrier((M), (N), 0)

__global__ __launch_bounds__(512, 2) void k_gemm(
    const unsigned short* __restrict__ A,   // (B_DIM, N_DIM) bf16
    const unsigned short* __restrict__ Bw,  // (M_DIM, N_DIM) bf16  (= W'')
    const float* __restrict__ SU,
    float* __restrict__ C) {                // (B_DIM, M_DIM) f32
    __shared__ __align__(16) unsigned short lds[4 * 16384];  // 128 KiB

    int t = threadIdx.x;
    int w = t >> 6;   // wave 0..7
    int l = t & 63;

    // XCD-aware tile mapping (bijective, 512 % 8 == 0) — R1 map.
    int lin = blockIdx.x;
    int xcd = lin & 7;
    int idx = lin >> 3;             // 0..63
    int bn = xcd * 2 + (idx >> 5);  // 0..15  (M tiles)
    int bm = idx & 31;              // 0..31  (B tiles)

    // staging: lane l writes LDS slot (row w*16 + l>>2, chunk l&3) of a
    // 128-row half; inverse-swizzled global source uses lx = l ^ (l>>3).
    int lx = l ^ (l >> 3);
    const unsigned short* aS0 =
        A + (size_t)(bm * 256 + w * 16 + (lx >> 2)) * N_DIM + (lx & 3) * 8;
    const unsigned short* aS1 = aS0 + (size_t)128 * N_DIM;
    const unsigned short* bS0 =
        Bw + (size_t)(bn * 256 + w * 16 + (lx >> 2)) * N_DIM + (lx & 3) * 8;
    const unsigned short* bS1 = bS0 + (size_t)128 * N_DIM;

    // fragment read byte-addresses (swizzled), as 32-bit LDS offsets
    int wm = w >> 2;   // 0..1  (M half)
    int wn = w & 3;    // 0..3  (N quarter)
    int quad = l >> 4;
    int ln = l & 15;
    unsigned ldsU = lds_u32(lds);
    unsigned aByte = ldsU +
        (unsigned)(((((wm * 128) + ln) << 6) | (quad << 4)) ^ ((ln >> 1) << 4));
    unsigned bByte = ldsU + 16384u +
        (unsigned)(((((wn * 64) + ln) << 6) | (quad << 4)) ^ ((ln >> 1) << 4));

    f32x4 acc[8][4];
#pragma unroll
    for (int i = 0; i < 8; i++)
#pragma unroll
        for (int j = 0; j < 4; j++) {
            f32x4 z = {0.f, 0.f, 0.f, 0.f};
            acc[i][j] = z;
        }

#define STAGE(KT) do {                                              \
        int kt_ = (KT);                                             \
        int ks_ = kt_ < 127 ? kt_ : 127;                            \
        unsigned short* d_ = lds + ((unsigned)kt_ & 3u) * 16384 + w * 512; \
        load_lds16(aS0 + ks_ * 32, d_);                             \
        load_lds16(aS1 + ks_ * 32, d_ + 4096);                      \
        load_lds16(bS0 + ks_ * 32, d_ + 8192);                      \
        load_lds16(bS1 + ks_ * 32, d_ + 12288);                     \
    } while (0)

#define GROUP(I, BC) do {                                           \
        acc[I][0] = __builtin_amdgcn_mfma_f32_16x16x32_bf16(        \
            af[I], BC[0], acc[I][0], 0, 0, 0);                      \
        acc[I][1] = __builtin_amdgcn_mfma_f32_16x16x32_bf16(        \
            af[I], BC[1], acc[I][1], 0, 0, 0);                      \
        acc[I][2] = __builtin_amdgcn_mfma_f32_16x16x32_bf16(        \
            af[I], BC[2], acc[I][2], 0, 0, 0);                      \
        acc[I][3] = __builtin_amdgcn_mfma_f32_16x16x32_bf16(        \
            af[I], BC[3], acc[I][3], 0, 0, 0);                      \
    } while (0)

    // BODY(k): MFMAs consume tile k (af + BC, loaded in iter k-1);
    // interleaved reads fill tile k+1 (af overwritten group-by-group + BN).
#define BODY(K, BC, BN) do {                                        \
        asm volatile("s_waitcnt lgkmcnt(0)");                       \
        SB0();  /* rule 18: MFMAs stay below; tile-K frags arrived */ \
        STAGE((K) + 3);                                             \
        unsigned aun = aByte + ((unsigned)((K) + 1) & 3u) * 32768u; \
        unsigned bun = bByte + ((unsigned)((K) + 1) & 3u) * 32768u; \
        SGB(0x10, 4);  /* 4 stage VMEM first */                     \
        GROUP(0, BC); DSR(af[0], aun, 0);    DSR(BN[0], bun, 0);    \
        SGB(0x8, 4); SGB(0x100, 2);                                 \
        GROUP(1, BC); DSR(af[1], aun, 1024); DSR(BN[1], bun, 1024); \
        SGB(0x8, 4); SGB(0x100, 2);                                 \
        GROUP(2, BC); DSR(af[2], aun, 2048); DSR(BN[2], bun, 2048); \
        SGB(0x8, 4); SGB(0x100, 2);                                 \
        GROUP(3, BC); DSR(af[3], aun, 3072); DSR(BN[3], bun, 3072); \
        SGB(0x8, 4); SGB(0x100, 2);                                 \
        GROUP(4, BC); DSR(af[4], aun, 4096);                        \
        SGB(0x8, 4); SGB(0x100, 1);                                 \
        GROUP(5, BC); DSR(af[5], aun, 5120);                        \
        SGB(0x8, 4); SGB(0x100, 1);                                 \
        GROUP(6, BC); DSR(af[6], aun, 6144);                        \
        SGB(0x8, 4); SGB(0x100, 1);                                 \
        GROUP(7, BC); DSR(af[7], aun, 7168);                        \
        SGB(0x8, 4); SGB(0x100, 1);                                 \
        asm volatile("s_waitcnt vmcnt(4)");  /* tile K+2 landed; >0 */ \
        asm volatile("" ::: "memory");                              \
        __builtin_amdgcn_s_barrier();                               \
        asm volatile("" ::: "memory");                              \
    } while (0)

    bf16x8 af[8], bfrA[4], bfrB[4];

    // prologue: stage 0..2; vmcnt(4) => tiles 0 AND 1 landed (only
    // STAGE(2) may be in flight) — BODY(0) reads tile 1 mid-body, so
    // tile 1 MUST be resident here (R6 bug: vmcnt(8) only covered tile 0).
    STAGE(0);
    STAGE(1);
    STAGE(2);
    asm volatile("s_waitcnt vmcnt(4)");
    __builtin_amdgcn_s_barrier();
    asm volatile("" ::: "memory");
    {
        unsigned au0 = aByte;
        unsigned bu0 = bByte;
        DSR(af[0], au0, 0);
        DSR(af[1], au0, 1024);
        DSR(af[2], au0, 2048);
        DSR(af[3], au0, 3072);
        DSR(af[4], au0, 4096);
        DSR(af[5], au0, 5120);
        DSR(af[6], au0, 6144);
        DSR(af[7], au0, 7168);
        DSR(bfrA[0], bu0, 0);
        DSR(bfrA[1], bu0, 1024);
        DSR(bfrA[2], bu0, 2048);
        DSR(bfrA[3], bu0, 3072);
    }

    for (int k = 0; k < N_DIM / 32; k += 2) {
        BODY(k, bfrA, bfrB);
        BODY(k + 1, bfrB, bfrA);
    }
    asm volatile("s_waitcnt vmcnt(0) lgkmcnt(0)");  // drain tail dummies

    // epilogue: C/D layout col=lane&15, row=quad*4+reg (m89/m91-verified)
#pragma unroll
    for (int j = 0; j < 4; j++) {
        int col = bn * 256 + wn * 64 + j * 16 + ln;
        float su = SU[col];
#pragma unroll
        for (int i = 0; i < 8; i++) {
#pragma unroll
            for (int r = 0; r < 4; r++) {
                int rowg = bm * 256 + wm * 128 + i * 16 + quad * 4 + r;
                C[(size_t)rowg * M_DIM + col] = acc[i][j][r] * su;
            }
        }
    }
#undef STAGE
#undef GROUP
#undef BODY
}

extern "C" void kernel_launch(void* const* d_in, const int* in_sizes, int n_in,
                              void* d_out, int out_size, void* d_ws, size_t ws_size,
                              hipStream_t stream) {
    const float* x    = (const float*)d_in[0];
    const int*   q1   = (const int*)d_in[1];
    const int*   q2   = (const int*)d_in[2];
    const float* SU   = (const float*)d_in[3];
    const float* SV   = (const float*)d_in[4];
    const float* cb1  = (const float*)d_in[5];
    const float* cb2  = (const float*)d_in[6];
    const float* wsp  = (const float*)d_in[7];
    const float* irsp = (const float*)d_in[8];
    float* out = (float*)d_out;  // reference output dtype: float32

    // workspace: x_rht bf16 (64MiB) | W bf16 (32MiB)  => 96MiB total
    unsigned short* xrht = (unsigned short*)d_ws;
    unsigned short* Wb   = xrht + (size_t)B_DIM * N_DIM;

    k_build_w<<<dim3((M_DIM * G_DIM) / 256), dim3(256), 0, stream>>>(
        q1, q2, cb1, cb2, wsp, irsp, Wb);
    // W'' = (1/64) H_4096 W  (column-direction Hadamard, two H64 passes)
    k_hadw<<<dim3(N_DIM / 256, 64), dim3(256), 0, stream>>>(Wb, 1, 64, 1.0f);
    k_hadw<<<dim3(N_DIM / 256, 64), dim3(256), 0, stream>>>(Wb, 64, 1, 0.015625f);
    k_rht_in<<<dim3(B_DIM), dim3(256), 0, stream>>>(x, SV, xrht);
    k_gemm<<<dim3(512), dim3(512), 0, stream>>>(xrht, Wb, SU, out);
}